// Round 2
// baseline (1502.211 us; speedup 1.0000x reference)
//
#include <hip/hip_runtime.h>
#include <hip/hip_bf16.h>
#include <stdint.h>

#define EPSV 1e-5f
#define BKLG 10
#define BK 1024
#define P1CHUNK 16384

// ---------------- init ----------------

// zero bucket counts (256) and BN stats (64) -- single block
__global__ void k_zero(int* __restrict__ bcnt, float* __restrict__ stats) {
  int t = threadIdx.x;
  bcnt[t] = 0;
  if (t < 64) stats[t] = 0.f;
}

// ---------------- graph build ----------------
// bucket = 1024 consecutive dst nodes (NB <= 256).
// 1) k_bcount: per-bucket edge counts (LDS histogram).
// 2) k_bscan:  exclusive scan -> bucket base offsets (ticket = cursors, bbeg).
// 3) k_bin:    bin edges into per-bucket staging streams (packed src|dstLocal).
// 4) k_dinv2:  per-bucket local-dst histogram -> dinv only (no CSR at all).
// Aggregation consumes the staged streams directly (see k_agg_lds).

__global__ __launch_bounds__(256) void k_bcount(const int* __restrict__ e32, int E, int NB,
                                                int* __restrict__ bcnt) {
  __shared__ int cnt[256];
  int t = threadIdx.x;
  cnt[t] = 0;
  __syncthreads();
  int e0 = blockIdx.x * P1CHUNK;
  int e1 = min(e0 + P1CHUNK, E);
  for (int i = e0 + t; i < e1; i += 256) {
    int d = e32[(size_t)E + i];
    atomicAdd(&cnt[d >> BKLG], 1);
  }
  __syncthreads();
  if (t < NB) {
    int c = cnt[t];
    if (c) atomicAdd(&bcnt[t], c);
  }
}

// exclusive scan of bcnt[NB] (NB<=256), single block
__global__ void k_bscan(const int* __restrict__ bcnt, int NB, int E,
                        int* __restrict__ ticket, int* __restrict__ bbeg) {
  __shared__ int sd[256];
  int t = threadIdx.x;
  int v = (t < NB) ? bcnt[t] : 0;
  sd[t] = v;
  __syncthreads();
  for (int st = 1; st < 256; st <<= 1) {
    int add = (t >= st) ? sd[t - st] : 0;
    __syncthreads();
    sd[t] += add;
    __syncthreads();
  }
  int ex = sd[t] - v;
  if (t < NB) {
    ticket[t] = ex;
    bbeg[t] = ex;
  }
  if (t == 0) bbeg[NB] = E;
}

// bin edges into per-bucket staging streams (packed src|dstLocal)
// requires N <= 2^18 (src packs in 18 bits) and NB <= 256
__global__ __launch_bounds__(256) void k_bin(const int* __restrict__ e32, int E, int NB,
                                             int* __restrict__ ticket,
                                             unsigned* __restrict__ staged) {
  __shared__ int cnt[256];
  __shared__ int base[256];
  int t = threadIdx.x;
  int e0 = blockIdx.x * P1CHUNK;
  int e1 = min(e0 + P1CHUNK, E);
  if (t < NB) cnt[t] = 0;
  __syncthreads();
  for (int i = e0 + t; i < e1; i += 256) {
    int d = e32[(size_t)E + i];
    atomicAdd(&cnt[d >> BKLG], 1);
  }
  __syncthreads();
  if (t < NB) {
    int c = cnt[t];
    base[t] = c ? atomicAdd(&ticket[t], c) : 0;
    cnt[t] = 0;
  }
  __syncthreads();
  for (int i = e0 + t; i < e1; i += 256) {
    int s = e32[i];
    int d = e32[(size_t)E + i];
    int b = d >> BKLG;
    int l = atomicAdd(&cnt[b], 1);
    staged[base[b] + l] = (unsigned)s | ((unsigned)(d & (BK - 1)) << 18);
  }
}

// per-bucket local-dst histogram -> dinv
__global__ __launch_bounds__(256) void k_dinv2(const unsigned* __restrict__ staged,
                                               const int* __restrict__ bbeg, int N,
                                               float* __restrict__ dinv) {
  __shared__ int hist[BK];
  int b = blockIdx.x, t = threadIdx.x;
  for (int i = t; i < BK; i += 256) hist[i] = 0;
  __syncthreads();
  int beg = bbeg[b], endp = bbeg[b + 1];
  for (int j = beg + t; j < endp; j += 256) atomicAdd(&hist[staged[j] >> 18], 1);
  __syncthreads();
  int n0 = b << BKLG;
  for (int i = t; i < BK; i += 256) {
    int gn = n0 + i;
    if (gn < N) dinv[gn] = rsqrtf((float)(hist[i] + 1));
  }
}

// ---------------- layer kernels ----------------

// hs[row] = (x[row] @ W) * dinv[row]   (x: N x 256, W: 256 x 16)
__global__ __launch_bounds__(256) void k_gemm1(const float* __restrict__ x,
                                               const float* __restrict__ W,
                                               const float* __restrict__ dinv, int N,
                                               float* __restrict__ hs) {
  int row = blockIdx.x * 256 + threadIdx.x;
  if (row >= N) return;
  const float4* xr = (const float4*)(x + (size_t)row * 256);
  float acc[16];
#pragma unroll
  for (int c = 0; c < 16; c++) acc[c] = 0.f;
#pragma unroll 8
  for (int j = 0; j < 64; j++) {
    float4 v = xr[j];
    const float* w0 = W + j * 64;  // W rows 4j..4j+3 (uniform -> s_load)
#pragma unroll
    for (int c = 0; c < 16; c++) {
      float t0 = fmaf(v.x, w0[c], acc[c]);
      float t1 = fmaf(v.y, w0[16 + c], t0);
      float t2 = fmaf(v.z, w0[32 + c], t1);
      acc[c] = fmaf(v.w, w0[48 + c], t2);
    }
  }
  float dv = dinv[row];
  float4* o4 = (float4*)(hs + (size_t)row * 16);
#pragma unroll
  for (int i = 0; i < 4; i++)
    o4[i] = make_float4(acc[i * 4] * dv, acc[i * 4 + 1] * dv, acc[i * 4 + 2] * dv,
                        acc[i * 4 + 3] * dv);
}

// bucket-local LDS-accumulator aggregation, edge-parallel over staged stream.
// out[d] = dinv[d]*(hs[d] + sum_{in} hs[src]) + bias;  optional fused BN stats.
// LDS acc rows use channel rotation (c+node)&15 so the 16 ds_add_f32 of a
// random-dst edge spread over all 32 banks (raw 16-stride would be 32-way).
__global__ __launch_bounds__(1024) void k_agg_lds(const float* __restrict__ hs,
                                                  const unsigned* __restrict__ staged,
                                                  const int* __restrict__ bbeg,
                                                  const float* __restrict__ dinv,
                                                  const float* __restrict__ bias, int N,
                                                  float* __restrict__ out,
                                                  float* __restrict__ stats, int do_stats) {
  __shared__ float acc[BK * 16];  // 64 KB
  int b = blockIdx.x, t = threadIdx.x;
  int n0 = b << BKLG;
  // init with self-loop term (or 0 past N)
#pragma unroll
  for (int k = 0; k < 16; k++) {
    int i = t + k * 1024;
    int node = i >> 4, c = i & 15;
    int gn = n0 + node;
    float v = (gn < N) ? hs[(size_t)gn * 16 + c] : 0.f;
    acc[(node << 4) + ((c + node) & 15)] = v;
  }
  __syncthreads();
  int beg = bbeg[b], endp = bbeg[b + 1];
  for (int j = beg + t; j < endp; j += 1024) {
    unsigned v = staged[j];
    int s = (int)(v & 0x3FFFFu);
    int dl = (int)(v >> 18);
    const float4* r4 = (const float4*)(hs + (size_t)s * 16);
    float4 q0 = r4[0], q1 = r4[1], q2 = r4[2], q3 = r4[3];
    float rv[16];
    rv[0] = q0.x; rv[1] = q0.y; rv[2] = q0.z; rv[3] = q0.w;
    rv[4] = q1.x; rv[5] = q1.y; rv[6] = q1.z; rv[7] = q1.w;
    rv[8] = q2.x; rv[9] = q2.y; rv[10] = q2.z; rv[11] = q2.w;
    rv[12] = q3.x; rv[13] = q3.y; rv[14] = q3.z; rv[15] = q3.w;
    int basei = dl << 4;
#pragma unroll
    for (int k = 0; k < 16; k++) atomicAdd(&acc[basei + ((k + dl) & 15)], rv[k]);
  }
  __syncthreads();
  // epilogue: scale+bias, write out, fold BN partial sums (c = t&15 is fixed)
  float s_sum = 0.f, s_sq = 0.f;
  int c = t & 15;
  float bi = bias[c];
#pragma unroll
  for (int k = 0; k < 16; k++) {
    int i = t + k * 1024;
    int node = i >> 4;
    int gn = n0 + node;
    if (gn < N) {
      float val = acc[(node << 4) + ((c + node) & 15)];
      float o = fmaf(val, dinv[gn], bi);
      out[(size_t)gn * 16 + c] = o;
      s_sum += o;
      s_sq = fmaf(o, o, s_sq);
    }
  }
  if (do_stats) {
    __syncthreads();  // done reading acc; reuse for reduction
    acc[t] = s_sum;
    acc[1024 + t] = s_sq;
    __syncthreads();
    for (int st = 512; st >= 16; st >>= 1) {
      if (t < st) { acc[t] += acc[t + st]; acc[1024 + t] += acc[1024 + t + st]; }
      __syncthreads();
    }
    if (t < 16) atomicAdd(&stats[t], acc[t]);
    else if (t < 32) atomicAdd(&stats[16 + (t - 16)], acc[1024 + (t - 16)]);
  }
}

// a = g*rsqrt(var+eps), s = be - mean*a
__global__ void k_affine(const float* __restrict__ stats, const float* __restrict__ g,
                         const float* __restrict__ be, float invN, float* __restrict__ a,
                         float* __restrict__ s) {
  int c = threadIdx.x;
  if (c < 16) {
    float mean = stats[c] * invN;
    float var = stats[16 + c] * invN - mean * mean;
    float av = g[c] * rsqrtf(var + EPSV);
    a[c] = av;
    s[c] = be[c] - mean * av;
  }
}

// hs_out[row] = (relu(a*in[row]+s) @ W) * dinv[row]   (W: 16x16)
__global__ void k_gemm_small(const float* __restrict__ in, const float* __restrict__ a,
                             const float* __restrict__ s, const float* __restrict__ W,
                             const float* __restrict__ dinv, int N, float* __restrict__ out) {
  int row = blockIdx.x * 256 + threadIdx.x;
  if (row >= N) return;
  const float4* in4 = (const float4*)(in + (size_t)row * 16);
  float v[16];
#pragma unroll
  for (int i = 0; i < 4; i++) {
    float4 tv = in4[i];
    v[i * 4 + 0] = tv.x; v[i * 4 + 1] = tv.y; v[i * 4 + 2] = tv.z; v[i * 4 + 3] = tv.w;
  }
#pragma unroll
  for (int c = 0; c < 16; c++) v[c] = fmaxf(fmaf(a[c], v[c], s[c]), 0.f);
  float acc[16];
#pragma unroll
  for (int c = 0; c < 16; c++) acc[c] = 0.f;
#pragma unroll
  for (int k = 0; k < 16; k++) {
#pragma unroll
    for (int c = 0; c < 16; c++) acc[c] = fmaf(v[k], W[k * 16 + c], acc[c]);
  }
  float dv = dinv[row];
  float4* o4 = (float4*)(out + (size_t)row * 16);
#pragma unroll
  for (int i = 0; i < 4; i++)
    o4[i] = make_float4(acc[i * 4] * dv, acc[i * 4 + 1] * dv, acc[i * 4 + 2] * dv,
                        acc[i * 4 + 3] * dv);
}

// ---------------- launch ----------------

extern "C" void kernel_launch(void* const* d_in, const int* in_sizes, int n_in,
                              void* d_out, int out_size, void* d_ws, size_t ws_size,
                              hipStream_t stream) {
  const float* x = (const float*)d_in[0];
  const int* eidx = (const int*)d_in[1];   // harness passes integers as int32
  const float* W1 = (const float*)d_in[2];
  const float* b1 = (const float*)d_in[3];
  const float* g1 = (const float*)d_in[4];
  const float* be1 = (const float*)d_in[5];
  const float* W2 = (const float*)d_in[6];
  const float* b2 = (const float*)d_in[7];
  const float* g2 = (const float*)d_in[8];
  const float* be2 = (const float*)d_in[9];
  const float* W3 = (const float*)d_in[10];
  const float* b3 = (const float*)d_in[11];
  float* out = (float*)d_out;

  int N = in_sizes[0] / 256;
  int E = in_sizes[1] / 2;
  int NB = (N + BK - 1) / BK;  // dst buckets (<=256 for N<=262144)

  // workspace layout (~27 MB; ws is ~800 MB per harness fill)
  char* w = (char*)d_ws;
  float* hs = (float*)w;                                   // N*16 floats = 12.8 MB
  unsigned* staged = (unsigned*)(w + (size_t)N * 16 * 4);  // E uints    = 12.8 MB
  char* p = w + (size_t)N * 16 * 4 + (size_t)E * 4;
  float* dinv = (float*)p;                                 // N floats
  p += (size_t)N * 4;
  float* stats1 = (float*)p;                               // 32
  float* stats2 = stats1 + 32;                             // 32
  float* a1 = stats2 + 32;
  float* s1 = a1 + 16;
  float* a2 = s1 + 16;
  float* s2 = a2 + 16;
  int* bcnt = (int*)(s2 + 16);                             // 256
  int* bbeg = bcnt + 256;                                  // 257 (pad 260)
  int* ticket = bbeg + 260;                                // 256

  int gN = (N + 255) / 256;
  int gB = (E + P1CHUNK - 1) / P1CHUNK;

  k_zero<<<1, 256, 0, stream>>>(bcnt, stats1);  // zeros bcnt + stats1/stats2
  k_bcount<<<gB, 256, 0, stream>>>(eidx, E, NB, bcnt);
  k_bscan<<<1, 256, 0, stream>>>(bcnt, NB, E, ticket, bbeg);
  k_bin<<<gB, 256, 0, stream>>>(eidx, E, NB, ticket, staged);
  k_dinv2<<<NB, 256, 0, stream>>>(staged, bbeg, N, dinv);

  float* o = out;  // use d_out as the BN-input ping buffer
  float invN = 1.f / (float)N;

  k_gemm1<<<gN, 256, 0, stream>>>(x, W1, dinv, N, hs);
  k_agg_lds<<<NB, 1024, 0, stream>>>(hs, staged, bbeg, dinv, b1, N, o, stats1, 1);
  k_affine<<<1, 64, 0, stream>>>(stats1, g1, be1, invN, a1, s1);
  k_gemm_small<<<gN, 256, 0, stream>>>(o, a1, s1, W2, dinv, N, hs);
  k_agg_lds<<<NB, 1024, 0, stream>>>(hs, staged, bbeg, dinv, b2, N, o, stats2, 1);
  k_affine<<<1, 64, 0, stream>>>(stats2, g2, be2, invN, a2, s2);
  k_gemm_small<<<gN, 256, 0, stream>>>(o, a2, s2, W3, dinv, N, hs);
  k_agg_lds<<<NB, 1024, 0, stream>>>(hs, staged, bbeg, dinv, b3, N, out, nullptr, 0);
}

// Round 3
// 1490.036 us; speedup vs baseline: 1.0082x; 1.0082x over previous
//
#include <hip/hip_runtime.h>
#include <hip/hip_bf16.h>
#include <stdint.h>

#define EPSV 1e-5f
#define BKLG 8
#define BK 256
#define P1CHUNK 16384
#define MAXNB 1024

// LDS accumulator slot for (node, channel): rotation uses node>>1 so the bank
// index 16*(node&1) + ((c+(node>>1))&15) covers all 32 banks for random nodes.
#define ROT(node, c) (((node) << 4) | (((c) + ((node) >> 1)) & 15))

// ---------------- init ----------------

// zero bucket counts (1024) and BN stats (64) -- single block of 1024
__global__ void k_zero(int* __restrict__ bcnt, float* __restrict__ stats) {
  int t = threadIdx.x;
  bcnt[t] = 0;
  if (t < 64) stats[t] = 0.f;
}

// ---------------- graph build ----------------
// bucket = 256 consecutive dst nodes (NB <= 1024; N=200000 -> NB=782).
// 1) k_bcount: per-bucket edge counts (LDS histogram).
// 2) k_bscan:  exclusive scan (1024-thread single block) -> ticket/bbeg.
// 3) k_bin:    bin edges into per-bucket staging streams (packed src|dstLocal).
// 4) k_dinv2:  per-bucket local-dst histogram -> dinv.
// Aggregation consumes the staged streams directly (k_agg_lds), no CSR.

__global__ __launch_bounds__(256) void k_bcount(const int* __restrict__ e32, int E, int NB,
                                                int* __restrict__ bcnt) {
  __shared__ int cnt[MAXNB];
  int t = threadIdx.x;
  for (int i = t; i < MAXNB; i += 256) cnt[i] = 0;
  __syncthreads();
  int e0 = blockIdx.x * P1CHUNK;
  int e1 = min(e0 + P1CHUNK, E);
  for (int i = e0 + t; i < e1; i += 256) {
    int d = e32[(size_t)E + i];
    atomicAdd(&cnt[d >> BKLG], 1);
  }
  __syncthreads();
  for (int i = t; i < NB; i += 256) {
    int c = cnt[i];
    if (c) atomicAdd(&bcnt[i], c);
  }
}

// exclusive scan of bcnt[NB] (NB<=1024), single 1024-thread block
__global__ void k_bscan(const int* __restrict__ bcnt, int NB, int E,
                        int* __restrict__ ticket, int* __restrict__ bbeg) {
  __shared__ int sd[1024];
  int t = threadIdx.x;
  int v = (t < NB) ? bcnt[t] : 0;
  sd[t] = v;
  __syncthreads();
  for (int st = 1; st < 1024; st <<= 1) {
    int add = (t >= st) ? sd[t - st] : 0;
    __syncthreads();
    sd[t] += add;
    __syncthreads();
  }
  int ex = sd[t] - v;
  if (t < NB) {
    ticket[t] = ex;
    bbeg[t] = ex;
  }
  if (t == 0) bbeg[NB] = E;
}

// bin edges into per-bucket staging streams (packed src | dstLocal<<18)
// requires N <= 2^18 (src packs in 18 bits) and NB <= 1024
__global__ __launch_bounds__(256) void k_bin(const int* __restrict__ e32, int E, int NB,
                                             int* __restrict__ ticket,
                                             unsigned* __restrict__ staged) {
  __shared__ int cnt[MAXNB];
  __shared__ int base[MAXNB];
  int t = threadIdx.x;
  int e0 = blockIdx.x * P1CHUNK;
  int e1 = min(e0 + P1CHUNK, E);
  for (int i = t; i < MAXNB; i += 256) cnt[i] = 0;
  __syncthreads();
  for (int i = e0 + t; i < e1; i += 256) {
    int d = e32[(size_t)E + i];
    atomicAdd(&cnt[d >> BKLG], 1);
  }
  __syncthreads();
  for (int i = t; i < NB; i += 256) {
    int c = cnt[i];
    base[i] = c ? atomicAdd(&ticket[i], c) : 0;
    cnt[i] = 0;
  }
  __syncthreads();
  for (int i = e0 + t; i < e1; i += 256) {
    int s = e32[i];
    int d = e32[(size_t)E + i];
    int b = d >> BKLG;
    int l = atomicAdd(&cnt[b], 1);
    staged[base[b] + l] = (unsigned)s | ((unsigned)(d & (BK - 1)) << 18);
  }
}

// per-bucket local-dst histogram -> dinv
__global__ __launch_bounds__(256) void k_dinv2(const unsigned* __restrict__ staged,
                                               const int* __restrict__ bbeg, int N,
                                               float* __restrict__ dinv) {
  __shared__ int hist[BK];
  int b = blockIdx.x, t = threadIdx.x;
  if (t < BK) hist[t] = 0;
  __syncthreads();
  int beg = bbeg[b], endp = bbeg[b + 1];
  for (int j = beg + t; j < endp; j += 256) atomicAdd(&hist[staged[j] >> 18], 1);
  __syncthreads();
  int gn = (b << BKLG) + t;
  if (t < BK && gn < N) dinv[gn] = rsqrtf((float)(hist[t] + 1));
}

// ---------------- layer kernels ----------------

// hs[row] = (x[row] @ W) * dinv[row]   (x: N x 256, W: 256 x 16)
__global__ __launch_bounds__(256) void k_gemm1(const float* __restrict__ x,
                                               const float* __restrict__ W,
                                               const float* __restrict__ dinv, int N,
                                               float* __restrict__ hs) {
  int row = blockIdx.x * 256 + threadIdx.x;
  if (row >= N) return;
  const float4* xr = (const float4*)(x + (size_t)row * 256);
  float acc[16];
#pragma unroll
  for (int c = 0; c < 16; c++) acc[c] = 0.f;
#pragma unroll 8
  for (int j = 0; j < 64; j++) {
    float4 v = xr[j];
    const float* w0 = W + j * 64;  // W rows 4j..4j+3 (uniform -> s_load)
#pragma unroll
    for (int c = 0; c < 16; c++) {
      float t0 = fmaf(v.x, w0[c], acc[c]);
      float t1 = fmaf(v.y, w0[16 + c], t0);
      float t2 = fmaf(v.z, w0[32 + c], t1);
      acc[c] = fmaf(v.w, w0[48 + c], t2);
    }
  }
  float dv = dinv[row];
  float4* o4 = (float4*)(hs + (size_t)row * 16);
#pragma unroll
  for (int i = 0; i < 4; i++)
    o4[i] = make_float4(acc[i * 4] * dv, acc[i * 4 + 1] * dv, acc[i * 4 + 2] * dv,
                        acc[i * 4 + 3] * dv);
}

// bucket-local LDS-accumulator aggregation, edge-parallel over staged stream.
// 256 nodes/bucket, 1024 threads/block, 16 KB LDS acc, 2-edge ILP unroll.
// out[d] = dinv[d]*(hs[d] + sum_{in} hs[src]) + bias;  optional fused BN stats.
__global__ __launch_bounds__(1024, 8) void k_agg_lds(const float* __restrict__ hs,
                                                     const unsigned* __restrict__ staged,
                                                     const int* __restrict__ bbeg,
                                                     const float* __restrict__ dinv,
                                                     const float* __restrict__ bias, int N,
                                                     float* __restrict__ out,
                                                     float* __restrict__ stats,
                                                     int do_stats) {
  __shared__ float acc[BK * 16];  // 16 KB
  int b = blockIdx.x, t = threadIdx.x;
  int n0 = b << BKLG;
  // init with self-loop term (or 0 past N); 4096 slots / 1024 threads
#pragma unroll
  for (int k = 0; k < 4; k++) {
    int i = t + k * 1024;
    int node = i >> 4, c = i & 15;
    int gn = n0 + node;
    float v = (gn < N) ? hs[(size_t)gn * 16 + c] : 0.f;
    acc[ROT(node, c)] = v;
  }
  __syncthreads();
  int beg = bbeg[b], endp = bbeg[b + 1];
  int j = beg + t;
  // 2-edge unrolled main loop: two gathers in flight per lane
  for (; j + 1024 < endp; j += 2048) {
    unsigned v0 = staged[j];
    unsigned v1 = staged[j + 1024];
    const float4* r0 = (const float4*)(hs + (size_t)(v0 & 0x3FFFFu) * 16);
    const float4* r1 = (const float4*)(hs + (size_t)(v1 & 0x3FFFFu) * 16);
    float4 a0 = r0[0], a1 = r0[1], a2 = r0[2], a3 = r0[3];
    float4 b0 = r1[0], b1 = r1[1], b2 = r1[2], b3 = r1[3];
    int d0 = (int)(v0 >> 18), d1 = (int)(v1 >> 18);
    int ba0 = d0 << 4, rt0 = d0 >> 1;
    int ba1 = d1 << 4, rt1 = d1 >> 1;
    float rv0[16] = {a0.x, a0.y, a0.z, a0.w, a1.x, a1.y, a1.z, a1.w,
                     a2.x, a2.y, a2.z, a2.w, a3.x, a3.y, a3.z, a3.w};
    float rv1[16] = {b0.x, b0.y, b0.z, b0.w, b1.x, b1.y, b1.z, b1.w,
                     b2.x, b2.y, b2.z, b2.w, b3.x, b3.y, b3.z, b3.w};
#pragma unroll
    for (int k = 0; k < 16; k++) atomicAdd(&acc[ba0 + ((k + rt0) & 15)], rv0[k]);
#pragma unroll
    for (int k = 0; k < 16; k++) atomicAdd(&acc[ba1 + ((k + rt1) & 15)], rv1[k]);
  }
  for (; j < endp; j += 1024) {
    unsigned v0 = staged[j];
    const float4* r0 = (const float4*)(hs + (size_t)(v0 & 0x3FFFFu) * 16);
    float4 a0 = r0[0], a1 = r0[1], a2 = r0[2], a3 = r0[3];
    int d0 = (int)(v0 >> 18);
    int ba0 = d0 << 4, rt0 = d0 >> 1;
    float rv0[16] = {a0.x, a0.y, a0.z, a0.w, a1.x, a1.y, a1.z, a1.w,
                     a2.x, a2.y, a2.z, a2.w, a3.x, a3.y, a3.z, a3.w};
#pragma unroll
    for (int k = 0; k < 16; k++) atomicAdd(&acc[ba0 + ((k + rt0) & 15)], rv0[k]);
  }
  __syncthreads();
  // epilogue: scale+bias, write out, fold BN partial sums (c = t&15 fixed)
  float s_sum = 0.f, s_sq = 0.f;
  int c = t & 15;
  float bi = bias[c];
#pragma unroll
  for (int k = 0; k < 4; k++) {
    int i = t + k * 1024;
    int node = i >> 4;
    int gn = n0 + node;
    if (gn < N) {
      float val = acc[ROT(node, c)];
      float o = fmaf(val, dinv[gn], bi);
      out[(size_t)gn * 16 + c] = o;
      s_sum += o;
      s_sq = fmaf(o, o, s_sq);
    }
  }
  if (do_stats) {
    __syncthreads();  // done reading acc; reuse for reduction
    acc[t] = s_sum;
    acc[1024 + t] = s_sq;
    __syncthreads();
    for (int st = 512; st >= 16; st >>= 1) {
      if (t < st) { acc[t] += acc[t + st]; acc[1024 + t] += acc[1024 + t + st]; }
      __syncthreads();
    }
    if (t < 16) atomicAdd(&stats[t], acc[t]);
    else if (t < 32) atomicAdd(&stats[16 + (t - 16)], acc[1024 + (t - 16)]);
  }
}

// a = g*rsqrt(var+eps), s = be - mean*a
__global__ void k_affine(const float* __restrict__ stats, const float* __restrict__ g,
                         const float* __restrict__ be, float invN, float* __restrict__ a,
                         float* __restrict__ s) {
  int c = threadIdx.x;
  if (c < 16) {
    float mean = stats[c] * invN;
    float var = stats[16 + c] * invN - mean * mean;
    float av = g[c] * rsqrtf(var + EPSV);
    a[c] = av;
    s[c] = be[c] - mean * av;
  }
}

// hs_out[row] = (relu(a*in[row]+s) @ W) * dinv[row]   (W: 16x16)
__global__ void k_gemm_small(const float* __restrict__ in, const float* __restrict__ a,
                             const float* __restrict__ s, const float* __restrict__ W,
                             const float* __restrict__ dinv, int N, float* __restrict__ out) {
  int row = blockIdx.x * 256 + threadIdx.x;
  if (row >= N) return;
  const float4* in4 = (const float4*)(in + (size_t)row * 16);
  float v[16];
#pragma unroll
  for (int i = 0; i < 4; i++) {
    float4 tv = in4[i];
    v[i * 4 + 0] = tv.x; v[i * 4 + 1] = tv.y; v[i * 4 + 2] = tv.z; v[i * 4 + 3] = tv.w;
  }
#pragma unroll
  for (int c = 0; c < 16; c++) v[c] = fmaxf(fmaf(a[c], v[c], s[c]), 0.f);
  float acc[16];
#pragma unroll
  for (int c = 0; c < 16; c++) acc[c] = 0.f;
#pragma unroll
  for (int k = 0; k < 16; k++) {
#pragma unroll
    for (int c = 0; c < 16; c++) acc[c] = fmaf(v[k], W[k * 16 + c], acc[c]);
  }
  float dv = dinv[row];
  float4* o4 = (float4*)(out + (size_t)row * 16);
#pragma unroll
  for (int i = 0; i < 4; i++)
    o4[i] = make_float4(acc[i * 4] * dv, acc[i * 4 + 1] * dv, acc[i * 4 + 2] * dv,
                        acc[i * 4 + 3] * dv);
}

// ---------------- launch ----------------

extern "C" void kernel_launch(void* const* d_in, const int* in_sizes, int n_in,
                              void* d_out, int out_size, void* d_ws, size_t ws_size,
                              hipStream_t stream) {
  const float* x = (const float*)d_in[0];
  const int* eidx = (const int*)d_in[1];   // harness passes integers as int32
  const float* W1 = (const float*)d_in[2];
  const float* b1 = (const float*)d_in[3];
  const float* g1 = (const float*)d_in[4];
  const float* be1 = (const float*)d_in[5];
  const float* W2 = (const float*)d_in[6];
  const float* b2 = (const float*)d_in[7];
  const float* g2 = (const float*)d_in[8];
  const float* be2 = (const float*)d_in[9];
  const float* W3 = (const float*)d_in[10];
  const float* b3 = (const float*)d_in[11];
  float* out = (float*)d_out;

  int N = in_sizes[0] / 256;
  int E = in_sizes[1] / 2;
  int NB = (N + BK - 1) / BK;  // dst buckets (<=1024 for N<=262144)

  // workspace layout (~27 MB; ws is ~800 MB per harness fill)
  char* w = (char*)d_ws;
  float* hs = (float*)w;                                   // N*16 floats = 12.8 MB
  unsigned* staged = (unsigned*)(w + (size_t)N * 16 * 4);  // E uints    = 12.8 MB
  char* p = w + (size_t)N * 16 * 4 + (size_t)E * 4;
  float* dinv = (float*)p;                                 // N floats
  p += (size_t)N * 4;
  float* stats1 = (float*)p;                               // 32
  float* stats2 = stats1 + 32;                             // 32
  float* a1 = stats2 + 32;
  float* s1 = a1 + 16;
  float* a2 = s1 + 16;
  float* s2 = a2 + 16;
  int* bcnt = (int*)(s2 + 16);                             // 1024
  int* bbeg = bcnt + 1024;                                 // 1025 (pad 1028)
  int* ticket = bbeg + 1028;                               // 1024

  int gN = (N + 255) / 256;
  int gB = (E + P1CHUNK - 1) / P1CHUNK;

  k_zero<<<1, 1024, 0, stream>>>(bcnt, stats1);  // zeros bcnt + stats1/stats2
  k_bcount<<<gB, 256, 0, stream>>>(eidx, E, NB, bcnt);
  k_bscan<<<1, 1024, 0, stream>>>(bcnt, NB, E, ticket, bbeg);
  k_bin<<<gB, 256, 0, stream>>>(eidx, E, NB, ticket, staged);
  k_dinv2<<<NB, 256, 0, stream>>>(staged, bbeg, N, dinv);

  float* o = out;  // use d_out as the BN-input ping buffer
  float invN = 1.f / (float)N;

  k_gemm1<<<gN, 256, 0, stream>>>(x, W1, dinv, N, hs);
  k_agg_lds<<<NB, 1024, 0, stream>>>(hs, staged, bbeg, dinv, b1, N, o, stats1, 1);
  k_affine<<<1, 64, 0, stream>>>(stats1, g1, be1, invN, a1, s1);
  k_gemm_small<<<gN, 256, 0, stream>>>(o, a1, s1, W2, dinv, N, hs);
  k_agg_lds<<<NB, 1024, 0, stream>>>(hs, staged, bbeg, dinv, b2, N, o, stats2, 1);
  k_affine<<<1, 64, 0, stream>>>(stats2, g2, be2, invN, a2, s2);
  k_gemm_small<<<gN, 256, 0, stream>>>(o, a2, s2, W3, dinv, N, hs);
  k_agg_lds<<<NB, 1024, 0, stream>>>(hs, staged, bbeg, dinv, b3, N, out, nullptr, 0);
}

// Round 4
// 1476.832 us; speedup vs baseline: 1.0172x; 1.0089x over previous
//
#include <hip/hip_runtime.h>
#include <hip/hip_bf16.h>
#include <stdint.h>

#define EPSV 1e-5f
#define BKLG 8
#define BK 256
#define P1CHUNK 16384
#define MAXNB 1024

// LDS accumulator slot for (node, channel): rotation uses node>>1 so the bank
// index 16*(node&1) + ((c+(node>>1))&15) covers all 32 banks for random nodes.
#define ROT(node, c) (((node) << 4) | (((c) + ((node) >> 1)) & 15))

// ---------------- init ----------------

// zero bucket counts (1024) and BN stats (64) -- single block of 1024
__global__ void k_zero(int* __restrict__ bcnt, float* __restrict__ stats) {
  int t = threadIdx.x;
  bcnt[t] = 0;
  if (t < 64) stats[t] = 0.f;
}

// ---------------- graph build ----------------
// bucket = 256 consecutive dst nodes (NB <= 1024; N=200000 -> NB=782).

__global__ __launch_bounds__(256) void k_bcount(const int* __restrict__ e32, int E, int NB,
                                                int* __restrict__ bcnt) {
  __shared__ int cnt[MAXNB];
  int t = threadIdx.x;
  for (int i = t; i < MAXNB; i += 256) cnt[i] = 0;
  __syncthreads();
  int e0 = blockIdx.x * P1CHUNK;
  int e1 = min(e0 + P1CHUNK, E);
  for (int i = e0 + t; i < e1; i += 256) {
    int d = e32[(size_t)E + i];
    atomicAdd(&cnt[d >> BKLG], 1);
  }
  __syncthreads();
  for (int i = t; i < NB; i += 256) {
    int c = cnt[i];
    if (c) atomicAdd(&bcnt[i], c);
  }
}

// exclusive scan of bcnt[NB] (NB<=1024), single 1024-thread block
__global__ void k_bscan(const int* __restrict__ bcnt, int NB, int E,
                        int* __restrict__ ticket, int* __restrict__ bbeg) {
  __shared__ int sd[1024];
  int t = threadIdx.x;
  int v = (t < NB) ? bcnt[t] : 0;
  sd[t] = v;
  __syncthreads();
  for (int st = 1; st < 1024; st <<= 1) {
    int add = (t >= st) ? sd[t - st] : 0;
    __syncthreads();
    sd[t] += add;
    __syncthreads();
  }
  int ex = sd[t] - v;
  if (t < NB) {
    ticket[t] = ex;
    bbeg[t] = ex;
  }
  if (t == 0) bbeg[NB] = E;
}

// bin edges into per-bucket staging streams (packed src | dstLocal<<18)
// requires N <= 2^18 (src packs in 18 bits) and NB <= 1024
__global__ __launch_bounds__(256) void k_bin(const int* __restrict__ e32, int E, int NB,
                                             int* __restrict__ ticket,
                                             unsigned* __restrict__ staged) {
  __shared__ int cnt[MAXNB];
  __shared__ int base[MAXNB];
  int t = threadIdx.x;
  int e0 = blockIdx.x * P1CHUNK;
  int e1 = min(e0 + P1CHUNK, E);
  for (int i = t; i < MAXNB; i += 256) cnt[i] = 0;
  __syncthreads();
  for (int i = e0 + t; i < e1; i += 256) {
    int d = e32[(size_t)E + i];
    atomicAdd(&cnt[d >> BKLG], 1);
  }
  __syncthreads();
  for (int i = t; i < NB; i += 256) {
    int c = cnt[i];
    base[i] = c ? atomicAdd(&ticket[i], c) : 0;
    cnt[i] = 0;
  }
  __syncthreads();
  for (int i = e0 + t; i < e1; i += 256) {
    int s = e32[i];
    int d = e32[(size_t)E + i];
    int b = d >> BKLG;
    int l = atomicAdd(&cnt[b], 1);
    staged[base[b] + l] = (unsigned)s | ((unsigned)(d & (BK - 1)) << 18);
  }
}

// per-bucket local-dst histogram -> dinv
__global__ __launch_bounds__(256) void k_dinv2(const unsigned* __restrict__ staged,
                                               const int* __restrict__ bbeg, int N,
                                               float* __restrict__ dinv) {
  __shared__ int hist[BK];
  int b = blockIdx.x, t = threadIdx.x;
  if (t < BK) hist[t] = 0;
  __syncthreads();
  int beg = bbeg[b], endp = bbeg[b + 1];
  for (int j = beg + t; j < endp; j += 256) atomicAdd(&hist[staged[j] >> 18], 1);
  __syncthreads();
  int gn = (b << BKLG) + t;
  if (t < BK && gn < N) dinv[gn] = rsqrtf((float)(hist[t] + 1));
}

// ---------------- layer kernels ----------------

// hs[row] = (x[row] @ W) * dinv[row]   (x: N x 256, W: 256 x 16)
__global__ __launch_bounds__(256) void k_gemm1(const float* __restrict__ x,
                                               const float* __restrict__ W,
                                               const float* __restrict__ dinv, int N,
                                               float* __restrict__ hs) {
  int row = blockIdx.x * 256 + threadIdx.x;
  if (row >= N) return;
  const float4* xr = (const float4*)(x + (size_t)row * 256);
  float acc[16];
#pragma unroll
  for (int c = 0; c < 16; c++) acc[c] = 0.f;
#pragma unroll 8
  for (int j = 0; j < 64; j++) {
    float4 v = xr[j];
    const float* w0 = W + j * 64;  // W rows 4j..4j+3 (uniform -> s_load)
#pragma unroll
    for (int c = 0; c < 16; c++) {
      float t0 = fmaf(v.x, w0[c], acc[c]);
      float t1 = fmaf(v.y, w0[16 + c], t0);
      float t2 = fmaf(v.z, w0[32 + c], t1);
      acc[c] = fmaf(v.w, w0[48 + c], t2);
    }
  }
  float dv = dinv[row];
  float4* o4 = (float4*)(hs + (size_t)row * 16);
#pragma unroll
  for (int i = 0; i < 4; i++)
    o4[i] = make_float4(acc[i * 4] * dv, acc[i * 4 + 1] * dv, acc[i * 4 + 2] * dv,
                        acc[i * 4 + 3] * dv);
}

// bucket-local LDS-accumulator aggregation, edge-parallel over staged stream.
// COOPERATIVE GATHER: 16 lanes = 16 channels of ONE edge's 64B row -> each
// wave-level load spans 4 cache lines (not 64). 64 edge-groups per block,
// stride-64 walk so a wave's 4 groups read consecutive staged words (1 line).
// One ds_add_f32 per edge per lane; 4-edge unroll for MLP.
__global__ __launch_bounds__(1024, 8) void k_agg_lds(const float* __restrict__ hs,
                                                     const unsigned* __restrict__ staged,
                                                     const int* __restrict__ bbeg,
                                                     const float* __restrict__ dinv,
                                                     const float* __restrict__ bias, int N,
                                                     float* __restrict__ out,
                                                     float* __restrict__ stats,
                                                     int do_stats) {
  __shared__ float acc[BK * 16];  // 16 KB
  int b = blockIdx.x, t = threadIdx.x;
  int n0 = b << BKLG;
  // init with self-loop term (or 0 past N); 4096 slots / 1024 threads
#pragma unroll
  for (int k = 0; k < 4; k++) {
    int i = t + k * 1024;
    int node = i >> 4, c0 = i & 15;
    int gn = n0 + node;
    float v = (gn < N) ? hs[(size_t)gn * 16 + c0] : 0.f;
    acc[ROT(node, c0)] = v;
  }
  __syncthreads();
  int beg = bbeg[b], endp = bbeg[b + 1];
  int c = t & 15;    // channel lane
  int g = t >> 4;    // edge group 0..63
  int j = beg + g;
  // 4-edge unrolled main loop: 4 independent line-gathers in flight per group
  for (; j + 192 < endp; j += 256) {
    unsigned v0 = staged[j];
    unsigned v1 = staged[j + 64];
    unsigned v2 = staged[j + 128];
    unsigned v3 = staged[j + 192];
    float x0 = hs[(size_t)(v0 & 0x3FFFFu) * 16 + c];
    float x1 = hs[(size_t)(v1 & 0x3FFFFu) * 16 + c];
    float x2 = hs[(size_t)(v2 & 0x3FFFFu) * 16 + c];
    float x3 = hs[(size_t)(v3 & 0x3FFFFu) * 16 + c];
    int d0 = (int)(v0 >> 18), d1 = (int)(v1 >> 18);
    int d2 = (int)(v2 >> 18), d3 = (int)(v3 >> 18);
    atomicAdd(&acc[ROT(d0, c)], x0);
    atomicAdd(&acc[ROT(d1, c)], x1);
    atomicAdd(&acc[ROT(d2, c)], x2);
    atomicAdd(&acc[ROT(d3, c)], x3);
  }
  for (; j < endp; j += 64) {
    unsigned v0 = staged[j];
    float x0 = hs[(size_t)(v0 & 0x3FFFFu) * 16 + c];
    int d0 = (int)(v0 >> 18);
    atomicAdd(&acc[ROT(d0, c)], x0);
  }
  __syncthreads();
  // epilogue: scale+bias, write out, fold BN partial sums (c = t&15 fixed)
  float s_sum = 0.f, s_sq = 0.f;
  float bi = bias[c];
#pragma unroll
  for (int k = 0; k < 4; k++) {
    int i = t + k * 1024;
    int node = i >> 4;
    int gn = n0 + node;
    if (gn < N) {
      float val = acc[ROT(node, c)];
      float o = fmaf(val, dinv[gn], bi);
      out[(size_t)gn * 16 + c] = o;
      s_sum += o;
      s_sq = fmaf(o, o, s_sq);
    }
  }
  if (do_stats) {
    __syncthreads();  // done reading acc; reuse for reduction
    acc[t] = s_sum;
    acc[1024 + t] = s_sq;
    __syncthreads();
    for (int st = 512; st >= 16; st >>= 1) {
      if (t < st) { acc[t] += acc[t + st]; acc[1024 + t] += acc[1024 + t + st]; }
      __syncthreads();
    }
    if (t < 16) atomicAdd(&stats[t], acc[t]);
    else if (t < 32) atomicAdd(&stats[16 + (t - 16)], acc[1024 + (t - 16)]);
  }
}

// a = g*rsqrt(var+eps), s = be - mean*a
__global__ void k_affine(const float* __restrict__ stats, const float* __restrict__ g,
                         const float* __restrict__ be, float invN, float* __restrict__ a,
                         float* __restrict__ s) {
  int c = threadIdx.x;
  if (c < 16) {
    float mean = stats[c] * invN;
    float var = stats[16 + c] * invN - mean * mean;
    float av = g[c] * rsqrtf(var + EPSV);
    a[c] = av;
    s[c] = be[c] - mean * av;
  }
}

// hs_out[row] = (relu(a*in[row]+s) @ W) * dinv[row]   (W: 16x16)
__global__ void k_gemm_small(const float* __restrict__ in, const float* __restrict__ a,
                             const float* __restrict__ s, const float* __restrict__ W,
                             const float* __restrict__ dinv, int N, float* __restrict__ out) {
  int row = blockIdx.x * 256 + threadIdx.x;
  if (row >= N) return;
  const float4* in4 = (const float4*)(in + (size_t)row * 16);
  float v[16];
#pragma unroll
  for (int i = 0; i < 4; i++) {
    float4 tv = in4[i];
    v[i * 4 + 0] = tv.x; v[i * 4 + 1] = tv.y; v[i * 4 + 2] = tv.z; v[i * 4 + 3] = tv.w;
  }
#pragma unroll
  for (int c = 0; c < 16; c++) v[c] = fmaxf(fmaf(a[c], v[c], s[c]), 0.f);
  float acc[16];
#pragma unroll
  for (int c = 0; c < 16; c++) acc[c] = 0.f;
#pragma unroll
  for (int k = 0; k < 16; k++) {
#pragma unroll
    for (int c = 0; c < 16; c++) acc[c] = fmaf(v[k], W[k * 16 + c], acc[c]);
  }
  float dv = dinv[row];
  float4* o4 = (float4*)(out + (size_t)row * 16);
#pragma unroll
  for (int i = 0; i < 4; i++)
    o4[i] = make_float4(acc[i * 4] * dv, acc[i * 4 + 1] * dv, acc[i * 4 + 2] * dv,
                        acc[i * 4 + 3] * dv);
}

// ---------------- launch ----------------

extern "C" void kernel_launch(void* const* d_in, const int* in_sizes, int n_in,
                              void* d_out, int out_size, void* d_ws, size_t ws_size,
                              hipStream_t stream) {
  const float* x = (const float*)d_in[0];
  const int* eidx = (const int*)d_in[1];   // harness passes integers as int32
  const float* W1 = (const float*)d_in[2];
  const float* b1 = (const float*)d_in[3];
  const float* g1 = (const float*)d_in[4];
  const float* be1 = (const float*)d_in[5];
  const float* W2 = (const float*)d_in[6];
  const float* b2 = (const float*)d_in[7];
  const float* g2 = (const float*)d_in[8];
  const float* be2 = (const float*)d_in[9];
  const float* W3 = (const float*)d_in[10];
  const float* b3 = (const float*)d_in[11];
  float* out = (float*)d_out;

  int N = in_sizes[0] / 256;
  int E = in_sizes[1] / 2;
  int NB = (N + BK - 1) / BK;  // dst buckets (<=1024 for N<=262144)

  // workspace layout (~27 MB; ws is ~800 MB per harness fill)
  char* w = (char*)d_ws;
  float* hs = (float*)w;                                   // N*16 floats = 12.8 MB
  unsigned* staged = (unsigned*)(w + (size_t)N * 16 * 4);  // E uints    = 12.8 MB
  char* p = w + (size_t)N * 16 * 4 + (size_t)E * 4;
  float* dinv = (float*)p;                                 // N floats
  p += (size_t)N * 4;
  float* stats1 = (float*)p;                               // 32
  float* stats2 = stats1 + 32;                             // 32
  float* a1 = stats2 + 32;
  float* s1 = a1 + 16;
  float* a2 = s1 + 16;
  float* s2 = a2 + 16;
  int* bcnt = (int*)(s2 + 16);                             // 1024
  int* bbeg = bcnt + 1024;                                 // 1025 (pad 1028)
  int* ticket = bbeg + 1028;                               // 1024

  int gN = (N + 255) / 256;
  int gB = (E + P1CHUNK - 1) / P1CHUNK;

  k_zero<<<1, 1024, 0, stream>>>(bcnt, stats1);  // zeros bcnt + stats1/stats2
  k_bcount<<<gB, 256, 0, stream>>>(eidx, E, NB, bcnt);
  k_bscan<<<1, 1024, 0, stream>>>(bcnt, NB, E, ticket, bbeg);
  k_bin<<<gB, 256, 0, stream>>>(eidx, E, NB, ticket, staged);
  k_dinv2<<<NB, 256, 0, stream>>>(staged, bbeg, N, dinv);

  float* o = out;  // use d_out as the BN-input ping buffer
  float invN = 1.f / (float)N;

  k_gemm1<<<gN, 256, 0, stream>>>(x, W1, dinv, N, hs);
  k_agg_lds<<<NB, 1024, 0, stream>>>(hs, staged, bbeg, dinv, b1, N, o, stats1, 1);
  k_affine<<<1, 64, 0, stream>>>(stats1, g1, be1, invN, a1, s1);
  k_gemm_small<<<gN, 256, 0, stream>>>(o, a1, s1, W2, dinv, N, hs);
  k_agg_lds<<<NB, 1024, 0, stream>>>(hs, staged, bbeg, dinv, b2, N, o, stats2, 1);
  k_affine<<<1, 64, 0, stream>>>(stats2, g2, be2, invN, a2, s2);
  k_gemm_small<<<gN, 256, 0, stream>>>(o, a2, s2, W3, dinv, N, hs);
  k_agg_lds<<<NB, 1024, 0, stream>>>(hs, staged, bbeg, dinv, b3, N, out, nullptr, 0);
}

// Round 5
// 1260.979 us; speedup vs baseline: 1.1913x; 1.1712x over previous
//
#include <hip/hip_runtime.h>
#include <hip/hip_bf16.h>
#include <stdint.h>

#define EPSV 1e-5f
#define BKLG 8
#define BK 256
#define P1CHUNK 16384
#define MAXNB 1024

// ---------------- init ----------------

// zero bucket counts (1024) and BN stats (64) -- single block of 1024
__global__ void k_zero(int* __restrict__ bcnt, float* __restrict__ stats) {
  int t = threadIdx.x;
  bcnt[t] = 0;
  if (t < 64) stats[t] = 0.f;
}

// ---------------- graph build ----------------
// bucket = 256 consecutive dst nodes (NB <= 1024; N=200000 -> NB=782).
// 1) k_bcount: per-bucket edge counts (LDS histogram).
// 2) k_bscan:  exclusive scan -> ticket/bbeg; offs[N]=E.
// 3) k_bin:    bin edges into per-bucket staging streams (packed src|dstLocal).
// 4) k_place:  per bucket: local-dst histogram + scan -> offs/dinv, scatter
//              src into contiguous CSR (single-writer lines per node).

__global__ __launch_bounds__(256) void k_bcount(const int* __restrict__ e32, int E, int NB,
                                                int* __restrict__ bcnt) {
  __shared__ int cnt[MAXNB];
  int t = threadIdx.x;
  for (int i = t; i < MAXNB; i += 256) cnt[i] = 0;
  __syncthreads();
  int e0 = blockIdx.x * P1CHUNK;
  int e1 = min(e0 + P1CHUNK, E);
  for (int i = e0 + t; i < e1; i += 256) {
    int d = e32[(size_t)E + i];
    atomicAdd(&cnt[d >> BKLG], 1);
  }
  __syncthreads();
  for (int i = t; i < NB; i += 256) {
    int c = cnt[i];
    if (c) atomicAdd(&bcnt[i], c);
  }
}

// exclusive scan of bcnt[NB] (NB<=1024), single 1024-thread block; offs[N]=E
__global__ void k_bscan(const int* __restrict__ bcnt, int NB, int E, int N,
                        int* __restrict__ ticket, int* __restrict__ bbeg,
                        int* __restrict__ offs) {
  __shared__ int sd[1024];
  int t = threadIdx.x;
  int v = (t < NB) ? bcnt[t] : 0;
  sd[t] = v;
  __syncthreads();
  for (int st = 1; st < 1024; st <<= 1) {
    int add = (t >= st) ? sd[t - st] : 0;
    __syncthreads();
    sd[t] += add;
    __syncthreads();
  }
  int ex = sd[t] - v;
  if (t < NB) {
    ticket[t] = ex;
    bbeg[t] = ex;
  }
  if (t == 0) {
    bbeg[NB] = E;
    offs[N] = E;
  }
}

// bin edges into per-bucket staging streams (packed src | dstLocal<<18)
// requires N <= 2^18 (src packs in 18 bits) and NB <= 1024
__global__ __launch_bounds__(256) void k_bin(const int* __restrict__ e32, int E, int NB,
                                             int* __restrict__ ticket,
                                             unsigned* __restrict__ staged) {
  __shared__ int cnt[MAXNB];
  __shared__ int base[MAXNB];
  int t = threadIdx.x;
  int e0 = blockIdx.x * P1CHUNK;
  int e1 = min(e0 + P1CHUNK, E);
  for (int i = t; i < MAXNB; i += 256) cnt[i] = 0;
  __syncthreads();
  for (int i = e0 + t; i < e1; i += 256) {
    int d = e32[(size_t)E + i];
    atomicAdd(&cnt[d >> BKLG], 1);
  }
  __syncthreads();
  for (int i = t; i < NB; i += 256) {
    int c = cnt[i];
    base[i] = c ? atomicAdd(&ticket[i], c) : 0;
    cnt[i] = 0;
  }
  __syncthreads();
  for (int i = e0 + t; i < e1; i += 256) {
    int s = e32[i];
    int d = e32[(size_t)E + i];
    int b = d >> BKLG;
    int l = atomicAdd(&cnt[b], 1);
    staged[base[b] + l] = (unsigned)s | ((unsigned)(d & (BK - 1)) << 18);
  }
}

// per bucket: hist -> scan -> offs/dinv, then scatter src into CSR
__global__ __launch_bounds__(256) void k_place(const unsigned* __restrict__ staged,
                                               const int* __restrict__ bbeg, int N,
                                               int* __restrict__ csr, int* __restrict__ offs,
                                               float* __restrict__ dinv) {
  __shared__ int hist[BK];
  __shared__ int sd[256];
  __shared__ int lpos[BK];
  int b = blockIdx.x, t = threadIdx.x;
  hist[t] = 0;
  __syncthreads();
  int beg = bbeg[b], endp = bbeg[b + 1];
  for (int j = beg + t; j < endp; j += 256) atomicAdd(&hist[staged[j] >> 18], 1);
  __syncthreads();
  int h = hist[t];
  sd[t] = h;
  __syncthreads();
  for (int st = 1; st < 256; st <<= 1) {
    int add = (t >= st) ? sd[t - st] : 0;
    __syncthreads();
    sd[t] += add;
    __syncthreads();
  }
  int ex = beg + sd[t] - h;  // exclusive within bucket
  lpos[t] = ex;
  int gn = (b << BKLG) + t;
  if (gn < N) {
    offs[gn] = ex;
    dinv[gn] = rsqrtf((float)(h + 1));
  }
  __syncthreads();
  for (int j = beg + t; j < endp; j += 256) {
    unsigned v = staged[j];
    int dl = (int)(v >> 18);
    int p = atomicAdd(&lpos[dl], 1);
    csr[p] = (int)(v & 0x3FFFFu);
  }
}

// ---------------- layer kernels ----------------

// hs[row] = (x[row] @ W) * dinv[row]   (x: N x 256, W: 256 x 16)
__global__ __launch_bounds__(256) void k_gemm1(const float* __restrict__ x,
                                               const float* __restrict__ W,
                                               const float* __restrict__ dinv, int N,
                                               float* __restrict__ hs) {
  int row = blockIdx.x * 256 + threadIdx.x;
  if (row >= N) return;
  const float4* xr = (const float4*)(x + (size_t)row * 256);
  float acc[16];
#pragma unroll
  for (int c = 0; c < 16; c++) acc[c] = 0.f;
#pragma unroll 8
  for (int j = 0; j < 64; j++) {
    float4 v = xr[j];
    const float* w0 = W + j * 64;  // W rows 4j..4j+3 (uniform -> s_load)
#pragma unroll
    for (int c = 0; c < 16; c++) {
      float t0 = fmaf(v.x, w0[c], acc[c]);
      float t1 = fmaf(v.y, w0[16 + c], t0);
      float t2 = fmaf(v.z, w0[32 + c], t1);
      acc[c] = fmaf(v.w, w0[48 + c], t2);
    }
  }
  float dv = dinv[row];
  float4* o4 = (float4*)(hs + (size_t)row * 16);
#pragma unroll
  for (int i = 0; i < 4; i++)
    o4[i] = make_float4(acc[i * 4] * dv, acc[i * 4 + 1] * dv, acc[i * 4 + 2] * dv,
                        acc[i * 4 + 3] * dv);
}

// out[d] = dinv[d]*(hs[d] + sum_{in} hs[src]) + bias  -- 4 lanes per node,
// 4-edge unrolled gather (4 independent lines in flight per node-group).
// Fused BN partial stats (sum, sumsq per channel) when do_stats.
__global__ __launch_bounds__(256) void k_agg(const float* __restrict__ hs,
                                             const int* __restrict__ csr,
                                             const int* __restrict__ offs,
                                             const float* __restrict__ dinv,
                                             const float* __restrict__ bias, int N,
                                             float* __restrict__ out,
                                             float* __restrict__ stats, int do_stats) {
  __shared__ float4 ss[256];
  __shared__ float4 sq[256];
  int t = threadIdx.x;
  int g = blockIdx.x * 256 + t;
  int node = g >> 2, q = g & 3;
  bool active = node < N;
  const float4* hs4 = (const float4*)hs;
  float4 a = make_float4(0.f, 0.f, 0.f, 0.f);
  if (active) {
    a = hs4[(size_t)node * 4 + q];  // self-loop term
    int beg = offs[node], end = offs[node + 1];
    int j = beg;
    for (; j + 3 < end; j += 4) {
      int s0 = csr[j], s1 = csr[j + 1], s2 = csr[j + 2], s3 = csr[j + 3];
      float4 v0 = hs4[(size_t)s0 * 4 + q];
      float4 v1 = hs4[(size_t)s1 * 4 + q];
      float4 v2 = hs4[(size_t)s2 * 4 + q];
      float4 v3 = hs4[(size_t)s3 * 4 + q];
      a.x += v0.x + v1.x + v2.x + v3.x;
      a.y += v0.y + v1.y + v2.y + v3.y;
      a.z += v0.z + v1.z + v2.z + v3.z;
      a.w += v0.w + v1.w + v2.w + v3.w;
    }
    for (; j < end; j++) {
      int s = csr[j];
      float4 v = hs4[(size_t)s * 4 + q];
      a.x += v.x; a.y += v.y; a.z += v.z; a.w += v.w;
    }
    float dv = dinv[node];
    float4 b = ((const float4*)bias)[q];
    a = make_float4(fmaf(a.x, dv, b.x), fmaf(a.y, dv, b.y), fmaf(a.z, dv, b.z),
                    fmaf(a.w, dv, b.w));
    ((float4*)out)[(size_t)node * 4 + q] = a;
  }
  if (do_stats) {
    float4 z = active ? a : make_float4(0.f, 0.f, 0.f, 0.f);
    ss[t] = z;
    sq[t] = make_float4(z.x * z.x, z.y * z.y, z.z * z.z, z.w * z.w);
    __syncthreads();
    // tree reduce; strides >= 4 keep q-classes (channel groups) aligned
    for (int st = 128; st >= 4; st >>= 1) {
      if (t < st) {
        float4 u = ss[t + st], w = sq[t + st];
        ss[t].x += u.x; ss[t].y += u.y; ss[t].z += u.z; ss[t].w += u.w;
        sq[t].x += w.x; sq[t].y += w.y; sq[t].z += w.z; sq[t].w += w.w;
      }
      __syncthreads();
    }
    if (t < 4) {
      float4 u = ss[t], w = sq[t];
      atomicAdd(&stats[t * 4 + 0], u.x);
      atomicAdd(&stats[t * 4 + 1], u.y);
      atomicAdd(&stats[t * 4 + 2], u.z);
      atomicAdd(&stats[t * 4 + 3], u.w);
      atomicAdd(&stats[16 + t * 4 + 0], w.x);
      atomicAdd(&stats[16 + t * 4 + 1], w.y);
      atomicAdd(&stats[16 + t * 4 + 2], w.z);
      atomicAdd(&stats[16 + t * 4 + 3], w.w);
    }
  }
}

// a = g*rsqrt(var+eps), s = be - mean*a
__global__ void k_affine(const float* __restrict__ stats, const float* __restrict__ g,
                         const float* __restrict__ be, float invN, float* __restrict__ a,
                         float* __restrict__ s) {
  int c = threadIdx.x;
  if (c < 16) {
    float mean = stats[c] * invN;
    float var = stats[16 + c] * invN - mean * mean;
    float av = g[c] * rsqrtf(var + EPSV);
    a[c] = av;
    s[c] = be[c] - mean * av;
  }
}

// hs_out[row] = (relu(a*in[row]+s) @ W) * dinv[row]   (W: 16x16)
__global__ void k_gemm_small(const float* __restrict__ in, const float* __restrict__ a,
                             const float* __restrict__ s, const float* __restrict__ W,
                             const float* __restrict__ dinv, int N, float* __restrict__ out) {
  int row = blockIdx.x * 256 + threadIdx.x;
  if (row >= N) return;
  const float4* in4 = (const float4*)(in + (size_t)row * 16);
  float v[16];
#pragma unroll
  for (int i = 0; i < 4; i++) {
    float4 tv = in4[i];
    v[i * 4 + 0] = tv.x; v[i * 4 + 1] = tv.y; v[i * 4 + 2] = tv.z; v[i * 4 + 3] = tv.w;
  }
#pragma unroll
  for (int c = 0; c < 16; c++) v[c] = fmaxf(fmaf(a[c], v[c], s[c]), 0.f);
  float acc[16];
#pragma unroll
  for (int c = 0; c < 16; c++) acc[c] = 0.f;
#pragma unroll
  for (int k = 0; k < 16; k++) {
#pragma unroll
    for (int c = 0; c < 16; c++) acc[c] = fmaf(v[k], W[k * 16 + c], acc[c]);
  }
  float dv = dinv[row];
  float4* o4 = (float4*)(out + (size_t)row * 16);
#pragma unroll
  for (int i = 0; i < 4; i++)
    o4[i] = make_float4(acc[i * 4] * dv, acc[i * 4 + 1] * dv, acc[i * 4 + 2] * dv,
                        acc[i * 4 + 3] * dv);
}

// ---------------- launch ----------------

extern "C" void kernel_launch(void* const* d_in, const int* in_sizes, int n_in,
                              void* d_out, int out_size, void* d_ws, size_t ws_size,
                              hipStream_t stream) {
  const float* x = (const float*)d_in[0];
  const int* eidx = (const int*)d_in[1];   // harness passes integers as int32
  const float* W1 = (const float*)d_in[2];
  const float* b1 = (const float*)d_in[3];
  const float* g1 = (const float*)d_in[4];
  const float* be1 = (const float*)d_in[5];
  const float* W2 = (const float*)d_in[6];
  const float* b2 = (const float*)d_in[7];
  const float* g2 = (const float*)d_in[8];
  const float* be2 = (const float*)d_in[9];
  const float* W3 = (const float*)d_in[10];
  const float* b3 = (const float*)d_in[11];
  float* out = (float*)d_out;

  int N = in_sizes[0] / 256;
  int E = in_sizes[1] / 2;
  int NB = (N + BK - 1) / BK;  // dst buckets (<=1024 for N<=262144)

  // workspace layout (~40 MB; ws is ~800 MB per harness fill)
  char* w = (char*)d_ws;
  float* hs = (float*)w;                                   // N*16 floats = 12.8 MB
  unsigned* staged = (unsigned*)(w + (size_t)N * 16 * 4);  // E uints    = 12.8 MB
  int* csr = (int*)(w + (size_t)N * 16 * 4 + (size_t)E * 4);  // E ints  = 12.8 MB
  char* p = w + (size_t)N * 16 * 4 + (size_t)E * 8;
  int* offs = (int*)p;                                     // (N+4) ints
  p += (size_t)(N + 4) * 4;
  float* dinv = (float*)p;                                 // N floats
  p += (size_t)N * 4;
  float* stats1 = (float*)p;                               // 32
  float* stats2 = stats1 + 32;                             // 32
  float* a1 = stats2 + 32;
  float* s1 = a1 + 16;
  float* a2 = s1 + 16;
  float* s2 = a2 + 16;
  int* bcnt = (int*)(s2 + 16);                             // 1024
  int* bbeg = bcnt + 1024;                                 // 1025 (pad 1028)
  int* ticket = bbeg + 1028;                               // 1024

  int gN = (N + 255) / 256;
  int gQ = (N * 4 + 255) / 256;
  int gB = (E + P1CHUNK - 1) / P1CHUNK;

  k_zero<<<1, 1024, 0, stream>>>(bcnt, stats1);  // zeros bcnt + stats1/stats2
  k_bcount<<<gB, 256, 0, stream>>>(eidx, E, NB, bcnt);
  k_bscan<<<1, 1024, 0, stream>>>(bcnt, NB, E, N, ticket, bbeg, offs);
  k_bin<<<gB, 256, 0, stream>>>(eidx, E, NB, ticket, staged);
  k_place<<<NB, 256, 0, stream>>>(staged, bbeg, N, csr, offs, dinv);

  float* o = out;  // use d_out as the BN-input ping buffer
  float invN = 1.f / (float)N;

  k_gemm1<<<gN, 256, 0, stream>>>(x, W1, dinv, N, hs);
  k_agg<<<gQ, 256, 0, stream>>>(hs, csr, offs, dinv, b1, N, o, stats1, 1);
  k_affine<<<1, 64, 0, stream>>>(stats1, g1, be1, invN, a1, s1);
  k_gemm_small<<<gN, 256, 0, stream>>>(o, a1, s1, W2, dinv, N, hs);
  k_agg<<<gQ, 256, 0, stream>>>(hs, csr, offs, dinv, b2, N, o, stats2, 1);
  k_affine<<<1, 64, 0, stream>>>(stats2, g2, be2, invN, a2, s2);
  k_gemm_small<<<gN, 256, 0, stream>>>(o, a2, s2, W3, dinv, N, hs);
  k_agg<<<gQ, 256, 0, stream>>>(hs, csr, offs, dinv, b3, N, out, nullptr, 0);
}

// Round 6
// 761.207 us; speedup vs baseline: 1.9735x; 1.6566x over previous
//
#include <hip/hip_runtime.h>
#include <hip/hip_bf16.h>
#include <stdint.h>

#define EPSV 1e-5f
#define BKLG 8
#define BK 256
#define P1CHUNK 16384
#define MAXNB 1024
#define DBINS 256  // degree bins for counting sort (clamped)

// ---------------- init ----------------

// zero bucket counts (1024), degree histogram (256), BN stats (64)
__global__ void k_zero(int* __restrict__ bcnt, int* __restrict__ dhist,
                       float* __restrict__ stats) {
  int t = threadIdx.x;
  bcnt[t] = 0;
  if (t < DBINS) dhist[t] = 0;
  if (t < 64) stats[t] = 0.f;
}

// ---------------- graph build ----------------
// bucket = 256 consecutive dst nodes (NB <= 1024; N=200000 -> NB=782).
// k_bcount/k_bscan/k_bin/k_place build CSR + offs + dinv without any global
// per-node atomic pass. Then k_deghist/k_dscan/k_permb counting-sort nodes
// by in-degree so k_agg waves see uniform edge-loop lengths (divergence fix).

__global__ __launch_bounds__(256) void k_bcount(const int* __restrict__ e32, int E, int NB,
                                                int* __restrict__ bcnt) {
  __shared__ int cnt[MAXNB];
  int t = threadIdx.x;
  for (int i = t; i < MAXNB; i += 256) cnt[i] = 0;
  __syncthreads();
  int e0 = blockIdx.x * P1CHUNK;
  int e1 = min(e0 + P1CHUNK, E);
  for (int i = e0 + t; i < e1; i += 256) {
    int d = e32[(size_t)E + i];
    atomicAdd(&cnt[d >> BKLG], 1);
  }
  __syncthreads();
  for (int i = t; i < NB; i += 256) {
    int c = cnt[i];
    if (c) atomicAdd(&bcnt[i], c);
  }
}

// exclusive scan of bcnt[NB] (NB<=1024), single 1024-thread block; offs[N]=E
__global__ void k_bscan(const int* __restrict__ bcnt, int NB, int E, int N,
                        int* __restrict__ ticket, int* __restrict__ bbeg,
                        int* __restrict__ offs) {
  __shared__ int sd[1024];
  int t = threadIdx.x;
  int v = (t < NB) ? bcnt[t] : 0;
  sd[t] = v;
  __syncthreads();
  for (int st = 1; st < 1024; st <<= 1) {
    int add = (t >= st) ? sd[t - st] : 0;
    __syncthreads();
    sd[t] += add;
    __syncthreads();
  }
  int ex = sd[t] - v;
  if (t < NB) {
    ticket[t] = ex;
    bbeg[t] = ex;
  }
  if (t == 0) {
    bbeg[NB] = E;
    offs[N] = E;
  }
}

// bin edges into per-bucket staging streams (packed src | dstLocal<<18)
// requires N <= 2^18 (src packs in 18 bits) and NB <= 1024
__global__ __launch_bounds__(256) void k_bin(const int* __restrict__ e32, int E, int NB,
                                             int* __restrict__ ticket,
                                             unsigned* __restrict__ staged) {
  __shared__ int cnt[MAXNB];
  __shared__ int base[MAXNB];
  int t = threadIdx.x;
  int e0 = blockIdx.x * P1CHUNK;
  int e1 = min(e0 + P1CHUNK, E);
  for (int i = t; i < MAXNB; i += 256) cnt[i] = 0;
  __syncthreads();
  for (int i = e0 + t; i < e1; i += 256) {
    int d = e32[(size_t)E + i];
    atomicAdd(&cnt[d >> BKLG], 1);
  }
  __syncthreads();
  for (int i = t; i < NB; i += 256) {
    int c = cnt[i];
    base[i] = c ? atomicAdd(&ticket[i], c) : 0;
    cnt[i] = 0;
  }
  __syncthreads();
  for (int i = e0 + t; i < e1; i += 256) {
    int s = e32[i];
    int d = e32[(size_t)E + i];
    int b = d >> BKLG;
    int l = atomicAdd(&cnt[b], 1);
    staged[base[b] + l] = (unsigned)s | ((unsigned)(d & (BK - 1)) << 18);
  }
}

// per bucket: hist -> scan -> offs/dinv, then scatter src into CSR
__global__ __launch_bounds__(256) void k_place(const unsigned* __restrict__ staged,
                                               const int* __restrict__ bbeg, int N,
                                               int* __restrict__ csr, int* __restrict__ offs,
                                               float* __restrict__ dinv) {
  __shared__ int hist[BK];
  __shared__ int sd[256];
  __shared__ int lpos[BK];
  int b = blockIdx.x, t = threadIdx.x;
  hist[t] = 0;
  __syncthreads();
  int beg = bbeg[b], endp = bbeg[b + 1];
  for (int j = beg + t; j < endp; j += 256) atomicAdd(&hist[staged[j] >> 18], 1);
  __syncthreads();
  int h = hist[t];
  sd[t] = h;
  __syncthreads();
  for (int st = 1; st < 256; st <<= 1) {
    int add = (t >= st) ? sd[t - st] : 0;
    __syncthreads();
    sd[t] += add;
    __syncthreads();
  }
  int ex = beg + sd[t] - h;  // exclusive within bucket
  lpos[t] = ex;
  int gn = (b << BKLG) + t;
  if (gn < N) {
    offs[gn] = ex;
    dinv[gn] = rsqrtf((float)(h + 1));
  }
  __syncthreads();
  for (int j = beg + t; j < endp; j += 256) {
    unsigned v = staged[j];
    int dl = (int)(v >> 18);
    int p = atomicAdd(&lpos[dl], 1);
    csr[p] = (int)(v & 0x3FFFFu);
  }
}

// ---------------- degree counting-sort (divergence fix) ----------------

// degree histogram (clamped to DBINS-1)
__global__ __launch_bounds__(256) void k_deghist(const int* __restrict__ offs, int N,
                                                 int* __restrict__ dhist) {
  __shared__ int dh[DBINS];
  int t = threadIdx.x;
  dh[t] = 0;
  __syncthreads();
  int n = blockIdx.x * 256 + t;
  if (n < N) {
    int deg = min(offs[n + 1] - offs[n], DBINS - 1);
    atomicAdd(&dh[deg], 1);
  }
  __syncthreads();
  int c = dh[t];
  if (c) atomicAdd(&dhist[t], c);
}

// exclusive scan of dhist -> dcursor (bin write cursors)
__global__ void k_dscan(const int* __restrict__ dhist, int* __restrict__ dcursor) {
  __shared__ int sd[DBINS];
  int t = threadIdx.x;
  int v = dhist[t];
  sd[t] = v;
  __syncthreads();
  for (int st = 1; st < DBINS; st <<= 1) {
    int add = (t >= st) ? sd[t - st] : 0;
    __syncthreads();
    sd[t] += add;
    __syncthreads();
  }
  dcursor[t] = sd[t] - v;
}

// binned permutation: perm[rank] = node, ranks grouped by degree
__global__ __launch_bounds__(256) void k_permb(const int* __restrict__ offs, int N,
                                               int* __restrict__ dcursor,
                                               int* __restrict__ perm) {
  __shared__ int cnt[DBINS];
  __shared__ int base[DBINS];
  int t = threadIdx.x;
  cnt[t] = 0;
  __syncthreads();
  int n = blockIdx.x * 256 + t;
  int bin = -1;
  if (n < N) {
    bin = min(offs[n + 1] - offs[n], DBINS - 1);
    atomicAdd(&cnt[bin], 1);
  }
  __syncthreads();
  int c = cnt[t];
  base[t] = c ? atomicAdd(&dcursor[t], c) : 0;
  cnt[t] = 0;
  __syncthreads();
  if (n < N) {
    int l = atomicAdd(&cnt[bin], 1);
    perm[base[bin] + l] = n;
  }
}

// ---------------- layer kernels ----------------

// hs[row] = (x[row] @ W) * dinv[row]   (x: N x 256, W: 256 x 16)
__global__ __launch_bounds__(256) void k_gemm1(const float* __restrict__ x,
                                               const float* __restrict__ W,
                                               const float* __restrict__ dinv, int N,
                                               float* __restrict__ hs) {
  int row = blockIdx.x * 256 + threadIdx.x;
  if (row >= N) return;
  const float4* xr = (const float4*)(x + (size_t)row * 256);
  float acc[16];
#pragma unroll
  for (int c = 0; c < 16; c++) acc[c] = 0.f;
#pragma unroll 8
  for (int j = 0; j < 64; j++) {
    float4 v = xr[j];
    const float* w0 = W + j * 64;  // W rows 4j..4j+3 (uniform -> s_load)
#pragma unroll
    for (int c = 0; c < 16; c++) {
      float t0 = fmaf(v.x, w0[c], acc[c]);
      float t1 = fmaf(v.y, w0[16 + c], t0);
      float t2 = fmaf(v.z, w0[32 + c], t1);
      acc[c] = fmaf(v.w, w0[48 + c], t2);
    }
  }
  float dv = dinv[row];
  float4* o4 = (float4*)(hs + (size_t)row * 16);
#pragma unroll
  for (int i = 0; i < 4; i++)
    o4[i] = make_float4(acc[i * 4] * dv, acc[i * 4 + 1] * dv, acc[i * 4 + 2] * dv,
                        acc[i * 4 + 3] * dv);
}

// out[d] = dinv[d]*(hs[d] + sum_{in} hs[src]) + bias  -- 4 lanes per node,
// EXACT R1 loop structure (no unroll, no LDS, no barriers: waves retire
// independently). Nodes processed in degree-sorted order via perm so each
// wave's 16 node-groups have (near-)equal edge counts.
__global__ void k_agg(const float* __restrict__ hs, const int* __restrict__ csr,
                      const int* __restrict__ offs, const int* __restrict__ perm,
                      const float* __restrict__ dinv, const float* __restrict__ bias,
                      int N, float* __restrict__ out) {
  int g = blockIdx.x * 256 + threadIdx.x;
  int r = g >> 2, q = g & 3;
  if (r >= N) return;
  int node = perm[r];
  int beg = offs[node], end = offs[node + 1];
  const float4* hs4 = (const float4*)hs;
  float4 a = hs4[(size_t)node * 4 + q];
  for (int j = beg; j < end; j++) {
    int s = csr[j];
    float4 v = hs4[(size_t)s * 4 + q];
    a.x += v.x; a.y += v.y; a.z += v.z; a.w += v.w;
  }
  float dv = dinv[node];
  float4 b = ((const float4*)bias)[q];
  ((float4*)out)[(size_t)node * 4 + q] =
      make_float4(fmaf(a.x, dv, b.x), fmaf(a.y, dv, b.y), fmaf(a.z, dv, b.z), fmaf(a.w, dv, b.w));
}

// per-channel sum / sumsq over rows
__global__ void k_bnstats(const float* __restrict__ o, int N, float* __restrict__ stats) {
  __shared__ float ss[256];
  __shared__ float sq[256];
  int t = threadIdx.x;
  int c = t & 15;
  int r = blockIdx.x * 16 + (t >> 4);
  int stride = gridDim.x * 16;
  float s = 0.f, q = 0.f;
  for (; r < N; r += stride) {
    float v = o[(size_t)r * 16 + c];
    s += v;
    q = fmaf(v, v, q);
  }
  ss[t] = s;
  sq[t] = q;
  __syncthreads();
  for (int st = 128; st >= 16; st >>= 1) {
    if (t < st) { ss[t] += ss[t + st]; sq[t] += sq[t + st]; }
    __syncthreads();
  }
  if (t < 16) {
    atomicAdd(&stats[t], ss[t]);
    atomicAdd(&stats[16 + t], sq[t]);
  }
}

// a = g*rsqrt(var+eps), s = be - mean*a
__global__ void k_affine(const float* __restrict__ stats, const float* __restrict__ g,
                         const float* __restrict__ be, float invN, float* __restrict__ a,
                         float* __restrict__ s) {
  int c = threadIdx.x;
  if (c < 16) {
    float mean = stats[c] * invN;
    float var = stats[16 + c] * invN - mean * mean;
    float av = g[c] * rsqrtf(var + EPSV);
    a[c] = av;
    s[c] = be[c] - mean * av;
  }
}

// hs_out[row] = (relu(a*in[row]+s) @ W) * dinv[row]   (W: 16x16)
__global__ void k_gemm_small(const float* __restrict__ in, const float* __restrict__ a,
                             const float* __restrict__ s, const float* __restrict__ W,
                             const float* __restrict__ dinv, int N, float* __restrict__ out) {
  int row = blockIdx.x * 256 + threadIdx.x;
  if (row >= N) return;
  const float4* in4 = (const float4*)(in + (size_t)row * 16);
  float v[16];
#pragma unroll
  for (int i = 0; i < 4; i++) {
    float4 tv = in4[i];
    v[i * 4 + 0] = tv.x; v[i * 4 + 1] = tv.y; v[i * 4 + 2] = tv.z; v[i * 4 + 3] = tv.w;
  }
#pragma unroll
  for (int c = 0; c < 16; c++) v[c] = fmaxf(fmaf(a[c], v[c], s[c]), 0.f);
  float acc[16];
#pragma unroll
  for (int c = 0; c < 16; c++) acc[c] = 0.f;
#pragma unroll
  for (int k = 0; k < 16; k++) {
#pragma unroll
    for (int c = 0; c < 16; c++) acc[c] = fmaf(v[k], W[k * 16 + c], acc[c]);
  }
  float dv = dinv[row];
  float4* o4 = (float4*)(out + (size_t)row * 16);
#pragma unroll
  for (int i = 0; i < 4; i++)
    o4[i] = make_float4(acc[i * 4] * dv, acc[i * 4 + 1] * dv, acc[i * 4 + 2] * dv,
                        acc[i * 4 + 3] * dv);
}

// ---------------- launch ----------------

extern "C" void kernel_launch(void* const* d_in, const int* in_sizes, int n_in,
                              void* d_out, int out_size, void* d_ws, size_t ws_size,
                              hipStream_t stream) {
  const float* x = (const float*)d_in[0];
  const int* eidx = (const int*)d_in[1];   // harness passes integers as int32
  const float* W1 = (const float*)d_in[2];
  const float* b1 = (const float*)d_in[3];
  const float* g1 = (const float*)d_in[4];
  const float* be1 = (const float*)d_in[5];
  const float* W2 = (const float*)d_in[6];
  const float* b2 = (const float*)d_in[7];
  const float* g2 = (const float*)d_in[8];
  const float* be2 = (const float*)d_in[9];
  const float* W3 = (const float*)d_in[10];
  const float* b3 = (const float*)d_in[11];
  float* out = (float*)d_out;

  int N = in_sizes[0] / 256;
  int E = in_sizes[1] / 2;
  int NB = (N + BK - 1) / BK;  // dst buckets (<=1024 for N<=262144)

  // workspace layout (~41 MB; ws is ~800 MB per harness fill)
  char* w = (char*)d_ws;
  float* hs = (float*)w;                                   // N*16 floats = 12.8 MB
  unsigned* staged = (unsigned*)(w + (size_t)N * 16 * 4);  // E uints    = 12.8 MB
  int* csr = (int*)(w + (size_t)N * 16 * 4 + (size_t)E * 4);  // E ints  = 12.8 MB
  char* p = w + (size_t)N * 16 * 4 + (size_t)E * 8;
  int* offs = (int*)p;                                     // (N+4) ints
  p += (size_t)(N + 4) * 4;
  float* dinv = (float*)p;                                 // N floats
  p += (size_t)N * 4;
  int* perm = (int*)p;                                     // N ints
  p += (size_t)N * 4;
  float* stats1 = (float*)p;                               // 32
  float* stats2 = stats1 + 32;                             // 32
  float* a1 = stats2 + 32;
  float* s1 = a1 + 16;
  float* a2 = s1 + 16;
  float* s2 = a2 + 16;
  int* bcnt = (int*)(s2 + 16);                             // 1024
  int* bbeg = bcnt + 1024;                                 // 1025 (pad 1028)
  int* ticket = bbeg + 1028;                               // 1024
  int* dhist = ticket + 1024;                              // 256
  int* dcursor = dhist + 256;                              // 256

  int gN = (N + 255) / 256;
  int gQ = (N * 4 + 255) / 256;
  int gB = (E + P1CHUNK - 1) / P1CHUNK;

  k_zero<<<1, 1024, 0, stream>>>(bcnt, dhist, stats1);  // zeros bcnt+dhist+stats
  k_bcount<<<gB, 256, 0, stream>>>(eidx, E, NB, bcnt);
  k_bscan<<<1, 1024, 0, stream>>>(bcnt, NB, E, N, ticket, bbeg, offs);
  k_bin<<<gB, 256, 0, stream>>>(eidx, E, NB, ticket, staged);
  k_place<<<NB, 256, 0, stream>>>(staged, bbeg, N, csr, offs, dinv);
  k_deghist<<<gN, 256, 0, stream>>>(offs, N, dhist);
  k_dscan<<<1, DBINS, 0, stream>>>(dhist, dcursor);
  k_permb<<<gN, 256, 0, stream>>>(offs, N, dcursor, perm);

  float* o = out;  // use d_out as the BN-input ping buffer
  float invN = 1.f / (float)N;

  k_gemm1<<<gN, 256, 0, stream>>>(x, W1, dinv, N, hs);
  k_agg<<<gQ, 256, 0, stream>>>(hs, csr, offs, perm, dinv, b1, N, o);
  k_bnstats<<<256, 256, 0, stream>>>(o, N, stats1);
  k_affine<<<1, 64, 0, stream>>>(stats1, g1, be1, invN, a1, s1);
  k_gemm_small<<<gN, 256, 0, stream>>>(o, a1, s1, W2, dinv, N, hs);
  k_agg<<<gQ, 256, 0, stream>>>(hs, csr, offs, perm, dinv, b2, N, o);
  k_bnstats<<<256, 256, 0, stream>>>(o, N, stats2);
  k_affine<<<1, 64, 0, stream>>>(stats2, g2, be2, invN, a2, s2);
  k_gemm_small<<<gN, 256, 0, stream>>>(o, a2, s2, W3, dinv, N, hs);
  k_agg<<<gQ, 256, 0, stream>>>(hs, csr, offs, perm, dinv, b3, N, out);
}

// Round 7
// 679.278 us; speedup vs baseline: 2.2115x; 1.1206x over previous
//
#include <hip/hip_runtime.h>
#include <hip/hip_bf16.h>
#include <stdint.h>

#define EPSV 1e-5f
#define BKLG 8
#define BK 256
#define P1CHUNK 16384
#define MAXNB 1024

// ---------------- init ----------------

// zero bucket counts (1024) and BN stats (64) -- single block of 1024
__global__ void k_zero(int* __restrict__ bcnt, float* __restrict__ stats) {
  int t = threadIdx.x;
  bcnt[t] = 0;
  if (t < 64) stats[t] = 0.f;
}

// ---------------- graph build ----------------
// bucket = 256 consecutive dst nodes (NB <= 1024; N=200000 -> NB=782).
// k_bcount/k_bscan/k_bin/k_place build CSR + offs + dinv with no global
// per-node atomic pass (the R0 k_edges was ~100MB of atomic traffic).

__global__ __launch_bounds__(256) void k_bcount(const int* __restrict__ e32, int E, int NB,
                                                int* __restrict__ bcnt) {
  __shared__ int cnt[MAXNB];
  int t = threadIdx.x;
  for (int i = t; i < MAXNB; i += 256) cnt[i] = 0;
  __syncthreads();
  int e0 = blockIdx.x * P1CHUNK;
  int e1 = min(e0 + P1CHUNK, E);
  for (int i = e0 + t; i < e1; i += 256) {
    int d = e32[(size_t)E + i];
    atomicAdd(&cnt[d >> BKLG], 1);
  }
  __syncthreads();
  for (int i = t; i < NB; i += 256) {
    int c = cnt[i];
    if (c) atomicAdd(&bcnt[i], c);
  }
}

// exclusive scan of bcnt[NB] (NB<=1024), single 1024-thread block; offs[N]=E
__global__ void k_bscan(const int* __restrict__ bcnt, int NB, int E, int N,
                        int* __restrict__ ticket, int* __restrict__ bbeg,
                        int* __restrict__ offs) {
  __shared__ int sd[1024];
  int t = threadIdx.x;
  int v = (t < NB) ? bcnt[t] : 0;
  sd[t] = v;
  __syncthreads();
  for (int st = 1; st < 1024; st <<= 1) {
    int add = (t >= st) ? sd[t - st] : 0;
    __syncthreads();
    sd[t] += add;
    __syncthreads();
  }
  int ex = sd[t] - v;
  if (t < NB) {
    ticket[t] = ex;
    bbeg[t] = ex;
  }
  if (t == 0) {
    bbeg[NB] = E;
    offs[N] = E;
  }
}

// bin edges into per-bucket staging streams (packed src | dstLocal<<18)
// requires N <= 2^18 (src packs in 18 bits) and NB <= 1024
__global__ __launch_bounds__(256) void k_bin(const int* __restrict__ e32, int E, int NB,
                                             int* __restrict__ ticket,
                                             unsigned* __restrict__ staged) {
  __shared__ int cnt[MAXNB];
  __shared__ int base[MAXNB];
  int t = threadIdx.x;
  int e0 = blockIdx.x * P1CHUNK;
  int e1 = min(e0 + P1CHUNK, E);
  for (int i = t; i < MAXNB; i += 256) cnt[i] = 0;
  __syncthreads();
  for (int i = e0 + t; i < e1; i += 256) {
    int d = e32[(size_t)E + i];
    atomicAdd(&cnt[d >> BKLG], 1);
  }
  __syncthreads();
  for (int i = t; i < NB; i += 256) {
    int c = cnt[i];
    base[i] = c ? atomicAdd(&ticket[i], c) : 0;
    cnt[i] = 0;
  }
  __syncthreads();
  for (int i = e0 + t; i < e1; i += 256) {
    int s = e32[i];
    int d = e32[(size_t)E + i];
    int b = d >> BKLG;
    int l = atomicAdd(&cnt[b], 1);
    staged[base[b] + l] = (unsigned)s | ((unsigned)(d & (BK - 1)) << 18);
  }
}

// per bucket: hist -> scan -> offs/dinv, then scatter src into CSR
__global__ __launch_bounds__(256) void k_place(const unsigned* __restrict__ staged,
                                               const int* __restrict__ bbeg, int N,
                                               int* __restrict__ csr, int* __restrict__ offs,
                                               float* __restrict__ dinv) {
  __shared__ int hist[BK];
  __shared__ int sd[256];
  __shared__ int lpos[BK];
  int b = blockIdx.x, t = threadIdx.x;
  hist[t] = 0;
  __syncthreads();
  int beg = bbeg[b], endp = bbeg[b + 1];
  for (int j = beg + t; j < endp; j += 256) atomicAdd(&hist[staged[j] >> 18], 1);
  __syncthreads();
  int h = hist[t];
  sd[t] = h;
  __syncthreads();
  for (int st = 1; st < 256; st <<= 1) {
    int add = (t >= st) ? sd[t - st] : 0;
    __syncthreads();
    sd[t] += add;
    __syncthreads();
  }
  int ex = beg + sd[t] - h;  // exclusive within bucket
  lpos[t] = ex;
  int gn = (b << BKLG) + t;
  if (gn < N) {
    offs[gn] = ex;
    dinv[gn] = rsqrtf((float)(h + 1));
  }
  __syncthreads();
  for (int j = beg + t; j < endp; j += 256) {
    unsigned v = staged[j];
    int dl = (int)(v >> 18);
    int p = atomicAdd(&lpos[dl], 1);
    csr[p] = (int)(v & 0x3FFFFu);
  }
}

// ---------------- layer kernels ----------------

// hs[row] = (x[row] @ W) * dinv[row]   (x: N x 256, W: 256 x 16)
__global__ __launch_bounds__(256) void k_gemm1(const float* __restrict__ x,
                                               const float* __restrict__ W,
                                               const float* __restrict__ dinv, int N,
                                               float* __restrict__ hs) {
  int row = blockIdx.x * 256 + threadIdx.x;
  if (row >= N) return;
  const float4* xr = (const float4*)(x + (size_t)row * 256);
  float acc[16];
#pragma unroll
  for (int c = 0; c < 16; c++) acc[c] = 0.f;
#pragma unroll 8
  for (int j = 0; j < 64; j++) {
    float4 v = xr[j];
    const float* w0 = W + j * 64;  // W rows 4j..4j+3 (uniform -> s_load)
#pragma unroll
    for (int c = 0; c < 16; c++) {
      float t0 = fmaf(v.x, w0[c], acc[c]);
      float t1 = fmaf(v.y, w0[16 + c], t0);
      float t2 = fmaf(v.z, w0[32 + c], t1);
      acc[c] = fmaf(v.w, w0[48 + c], t2);
    }
  }
  float dv = dinv[row];
  float4* o4 = (float4*)(hs + (size_t)row * 16);
#pragma unroll
  for (int i = 0; i < 4; i++)
    o4[i] = make_float4(acc[i * 4] * dv, acc[i * 4 + 1] * dv, acc[i * 4 + 2] * dv,
                        acc[i * 4 + 3] * dv);
}

// out[d] = dinv[d]*(hs[d] + sum_{in} hs[src]) + bias  -- 4 lanes per node.
// R1-exact structure (no perm, no LDS, no barriers; waves retire
// independently) + 2-edge unroll so each node-group keeps 2 gather
// misses in flight instead of 1.
__global__ void k_agg(const float* __restrict__ hs, const int* __restrict__ csr,
                      const int* __restrict__ offs, const float* __restrict__ dinv,
                      const float* __restrict__ bias, int N, float* __restrict__ out) {
  int g = blockIdx.x * 256 + threadIdx.x;
  int node = g >> 2, q = g & 3;
  if (node >= N) return;
  int beg = offs[node], end = offs[node + 1];
  const float4* hs4 = (const float4*)hs;
  float4 a = hs4[(size_t)node * 4 + q];
  int j = beg;
  for (; j + 1 < end; j += 2) {
    int s0 = csr[j];
    int s1 = csr[j + 1];
    float4 v0 = hs4[(size_t)s0 * 4 + q];
    float4 v1 = hs4[(size_t)s1 * 4 + q];
    a.x += v0.x + v1.x;
    a.y += v0.y + v1.y;
    a.z += v0.z + v1.z;
    a.w += v0.w + v1.w;
  }
  if (j < end) {
    int s = csr[j];
    float4 v = hs4[(size_t)s * 4 + q];
    a.x += v.x; a.y += v.y; a.z += v.z; a.w += v.w;
  }
  float dv = dinv[node];
  float4 b = ((const float4*)bias)[q];
  ((float4*)out)[(size_t)node * 4 + q] =
      make_float4(fmaf(a.x, dv, b.x), fmaf(a.y, dv, b.y), fmaf(a.z, dv, b.z), fmaf(a.w, dv, b.w));
}

// per-channel sum / sumsq over rows
__global__ void k_bnstats(const float* __restrict__ o, int N, float* __restrict__ stats) {
  __shared__ float ss[256];
  __shared__ float sq[256];
  int t = threadIdx.x;
  int c = t & 15;
  int r = blockIdx.x * 16 + (t >> 4);
  int stride = gridDim.x * 16;
  float s = 0.f, q = 0.f;
  for (; r < N; r += stride) {
    float v = o[(size_t)r * 16 + c];
    s += v;
    q = fmaf(v, v, q);
  }
  ss[t] = s;
  sq[t] = q;
  __syncthreads();
  for (int st = 128; st >= 16; st >>= 1) {
    if (t < st) { ss[t] += ss[t + st]; sq[t] += sq[t + st]; }
    __syncthreads();
  }
  if (t < 16) {
    atomicAdd(&stats[t], ss[t]);
    atomicAdd(&stats[16 + t], sq[t]);
  }
}

// a = g*rsqrt(var+eps), s = be - mean*a
__global__ void k_affine(const float* __restrict__ stats, const float* __restrict__ g,
                         const float* __restrict__ be, float invN, float* __restrict__ a,
                         float* __restrict__ s) {
  int c = threadIdx.x;
  if (c < 16) {
    float mean = stats[c] * invN;
    float var = stats[16 + c] * invN - mean * mean;
    float av = g[c] * rsqrtf(var + EPSV);
    a[c] = av;
    s[c] = be[c] - mean * av;
  }
}

// hs_out[row] = (relu(a*in[row]+s) @ W) * dinv[row]   (W: 16x16)
__global__ void k_gemm_small(const float* __restrict__ in, const float* __restrict__ a,
                             const float* __restrict__ s, const float* __restrict__ W,
                             const float* __restrict__ dinv, int N, float* __restrict__ out) {
  int row = blockIdx.x * 256 + threadIdx.x;
  if (row >= N) return;
  const float4* in4 = (const float4*)(in + (size_t)row * 16);
  float v[16];
#pragma unroll
  for (int i = 0; i < 4; i++) {
    float4 tv = in4[i];
    v[i * 4 + 0] = tv.x; v[i * 4 + 1] = tv.y; v[i * 4 + 2] = tv.z; v[i * 4 + 3] = tv.w;
  }
#pragma unroll
  for (int c = 0; c < 16; c++) v[c] = fmaxf(fmaf(a[c], v[c], s[c]), 0.f);
  float acc[16];
#pragma unroll
  for (int c = 0; c < 16; c++) acc[c] = 0.f;
#pragma unroll
  for (int k = 0; k < 16; k++) {
#pragma unroll
    for (int c = 0; c < 16; c++) acc[c] = fmaf(v[k], W[k * 16 + c], acc[c]);
  }
  float dv = dinv[row];
  float4* o4 = (float4*)(out + (size_t)row * 16);
#pragma unroll
  for (int i = 0; i < 4; i++)
    o4[i] = make_float4(acc[i * 4] * dv, acc[i * 4 + 1] * dv, acc[i * 4 + 2] * dv,
                        acc[i * 4 + 3] * dv);
}

// ---------------- launch ----------------

extern "C" void kernel_launch(void* const* d_in, const int* in_sizes, int n_in,
                              void* d_out, int out_size, void* d_ws, size_t ws_size,
                              hipStream_t stream) {
  const float* x = (const float*)d_in[0];
  const int* eidx = (const int*)d_in[1];   // harness passes integers as int32
  const float* W1 = (const float*)d_in[2];
  const float* b1 = (const float*)d_in[3];
  const float* g1 = (const float*)d_in[4];
  const float* be1 = (const float*)d_in[5];
  const float* W2 = (const float*)d_in[6];
  const float* b2 = (const float*)d_in[7];
  const float* g2 = (const float*)d_in[8];
  const float* be2 = (const float*)d_in[9];
  const float* W3 = (const float*)d_in[10];
  const float* b3 = (const float*)d_in[11];
  float* out = (float*)d_out;

  int N = in_sizes[0] / 256;
  int E = in_sizes[1] / 2;
  int NB = (N + BK - 1) / BK;  // dst buckets (<=1024 for N<=262144)

  // workspace layout (~40 MB; ws is ~800 MB per harness fill)
  char* w = (char*)d_ws;
  float* hs = (float*)w;                                   // N*16 floats = 12.8 MB
  unsigned* staged = (unsigned*)(w + (size_t)N * 16 * 4);  // E uints    = 12.8 MB
  int* csr = (int*)(w + (size_t)N * 16 * 4 + (size_t)E * 4);  // E ints  = 12.8 MB
  char* p = w + (size_t)N * 16 * 4 + (size_t)E * 8;
  int* offs = (int*)p;                                     // (N+4) ints
  p += (size_t)(N + 4) * 4;
  float* dinv = (float*)p;                                 // N floats
  p += (size_t)N * 4;
  float* stats1 = (float*)p;                               // 32
  float* stats2 = stats1 + 32;                             // 32
  float* a1 = stats2 + 32;
  float* s1 = a1 + 16;
  float* a2 = s1 + 16;
  float* s2 = a2 + 16;
  int* bcnt = (int*)(s2 + 16);                             // 1024
  int* bbeg = bcnt + 1024;                                 // 1025 (pad 1028)
  int* ticket = bbeg + 1028;                               // 1024

  int gN = (N + 255) / 256;
  int gQ = (N * 4 + 255) / 256;
  int gB = (E + P1CHUNK - 1) / P1CHUNK;

  k_zero<<<1, 1024, 0, stream>>>(bcnt, stats1);  // zeros bcnt + stats1/stats2
  k_bcount<<<gB, 256, 0, stream>>>(eidx, E, NB, bcnt);
  k_bscan<<<1, 1024, 0, stream>>>(bcnt, NB, E, N, ticket, bbeg, offs);
  k_bin<<<gB, 256, 0, stream>>>(eidx, E, NB, ticket, staged);
  k_place<<<NB, 256, 0, stream>>>(staged, bbeg, N, csr, offs, dinv);

  float* o = out;  // use d_out as the BN-input ping buffer
  float invN = 1.f / (float)N;

  k_gemm1<<<gN, 256, 0, stream>>>(x, W1, dinv, N, hs);
  k_agg<<<gQ, 256, 0, stream>>>(hs, csr, offs, dinv, b1, N, o);
  k_bnstats<<<256, 256, 0, stream>>>(o, N, stats1);
  k_affine<<<1, 64, 0, stream>>>(stats1, g1, be1, invN, a1, s1);
  k_gemm_small<<<gN, 256, 0, stream>>>(o, a1, s1, W2, dinv, N, hs);
  k_agg<<<gQ, 256, 0, stream>>>(hs, csr, offs, dinv, b2, N, o);
  k_bnstats<<<256, 256, 0, stream>>>(o, N, stats2);
  k_affine<<<1, 64, 0, stream>>>(stats2, g2, be2, invN, a2, s2);
  k_gemm_small<<<gN, 256, 0, stream>>>(o, a2, s2, W3, dinv, N, hs);
  k_agg<<<gQ, 256, 0, stream>>>(hs, csr, offs, dinv, b3, N, out);
}